// Round 1
// baseline (1348.969 us; speedup 1.0000x reference)
//
#include <hip/hip_runtime.h>

// Problem constants
#define NT 89       // n_labels
#define NB 1024     // batch
#define NE 300      // word_emb
#define NEP 320     // padded e
#define K1 1024     // ctx part of in_dim
#define NDIM 1324   // full in_dim

// GEMM tiling
#define BM 64
#define BK 32
#define AS_STRIDE 68    // 64 + 4 pad (keeps float4 align, shifts banks)
#define WS_STRIDE 324   // 320 + 4 pad

// ---------------------------------------------------------------------------
// Kernel 0: men_part[b][e] = bias[e] + sum_d men[b,d] * W[e, 1024+d]  (e<300),
//           0 for e in [300,320). One block per b.
// ---------------------------------------------------------------------------
__global__ void menpart_kernel(const float* __restrict__ men,
                               const float* __restrict__ W,
                               const float* __restrict__ bias,
                               float* __restrict__ men_part) {
    const int b = blockIdx.x;
    const int e = threadIdx.x;   // 0..319
    __shared__ float ms[NE];
    if (e < NE) ms[e] = men[b * NE + e];
    __syncthreads();
    float acc = 0.0f;
    if (e < NE) {
        const float* wrow = W + (size_t)e * NDIM + K1;
        acc = bias[e];
        #pragma unroll 4
        for (int d = 0; d < NE; ++d) acc = fmaf(ms[d], wrow[d], acc);
    }
    men_part[(size_t)b * NEP + e] = (e < NE) ? acc : 0.0f;
}

// ---------------------------------------------------------------------------
// Kernel 1: scores[t][b] = sum_e relu( ctx[t,b,:]·W[e,:1024] + men_part[b,e] )
//                          * types[t,e]
// Block: 64 b-rows of one t. 256 threads as 16(tx=e) x 16(ty=b).
// Each thread: acc[4 b][20 e] registers covering all 320 padded e.
// ---------------------------------------------------------------------------
__launch_bounds__(256, 2)
__global__ void scores_kernel(const float* __restrict__ ctx,
                              const float* __restrict__ W,
                              const float* __restrict__ types,
                              const float* __restrict__ men_part,
                              float* __restrict__ scores) {
    const int bt = blockIdx.x;          // 0..15  (b tile)
    const int t  = blockIdx.y;          // 0..88
    const int tid = threadIdx.x;
    const int tx = tid & 15;            // e direction
    const int ty = tid >> 4;            // b direction
    const int b0 = bt * BM;

    __shared__ float As[BK * AS_STRIDE];   // As[k][b]
    __shared__ float Ws[BK * WS_STRIDE];   // Ws[k][e]
    __shared__ float ts[NEP];              // types[t][e], 0-padded

    // stage types row (read only in epilogue; barriers in k-loop protect it)
    {
        int e = tid;
        ts[e] = (e < NE) ? types[(size_t)t * NE + e] : 0.0f;
        if (tid < NEP - 256) {
            int e2 = 256 + tid;
            ts[e2] = (e2 < NE) ? types[(size_t)t * NE + e2] : 0.0f;
        }
    }

    float acc[4][20];
    #pragma unroll
    for (int i = 0; i < 4; ++i)
        #pragma unroll
        for (int j = 0; j < 20; ++j) acc[i][j] = 0.0f;

    const float* ctx_base = ctx + ((size_t)t * NB + b0) * K1;

    for (int kt = 0; kt < K1 / BK; ++kt) {
        const int k0 = kt * BK;
        __syncthreads();
        // stage A tile: 64 rows x 32 k, transposed into As[k][b]
        #pragma unroll
        for (int m = 0; m < 2; ++m) {
            int id = m * 256 + tid;
            int row = id >> 3, vc = id & 7;
            float4 v = *(const float4*)(ctx_base + (size_t)row * K1 + k0 + vc * 4);
            int kk = vc * 4;
            As[(kk + 0) * AS_STRIDE + row] = v.x;
            As[(kk + 1) * AS_STRIDE + row] = v.y;
            As[(kk + 2) * AS_STRIDE + row] = v.z;
            As[(kk + 3) * AS_STRIDE + row] = v.w;
        }
        // stage W tile: 320 e-rows x 32 k, transposed into Ws[k][e]; zero e>=300
        #pragma unroll
        for (int m = 0; m < 10; ++m) {
            int id = m * 256 + tid;
            int row = id >> 3, vc = id & 7;   // row = e
            float4 v;
            if (row < NE) v = *(const float4*)(W + (size_t)row * NDIM + k0 + vc * 4);
            else          v = make_float4(0.f, 0.f, 0.f, 0.f);
            int kk = vc * 4;
            Ws[(kk + 0) * WS_STRIDE + row] = v.x;
            Ws[(kk + 1) * WS_STRIDE + row] = v.y;
            Ws[(kk + 2) * WS_STRIDE + row] = v.z;
            Ws[(kk + 3) * WS_STRIDE + row] = v.w;
        }
        __syncthreads();

        #pragma unroll
        for (int k = 0; k < BK; ++k) {
            float4 a4 = *(const float4*)(As + k * AS_STRIDE + ty * 4);
            float a[4] = {a4.x, a4.y, a4.z, a4.w};
            float w[20];
            #pragma unroll
            for (int et = 0; et < 5; ++et) {
                float4 w4 = *(const float4*)(Ws + k * WS_STRIDE + et * 64 + tx * 4);
                w[et * 4 + 0] = w4.x;
                w[et * 4 + 1] = w4.y;
                w[et * 4 + 2] = w4.z;
                w[et * 4 + 3] = w4.w;
            }
            #pragma unroll
            for (int i = 0; i < 4; ++i)
                #pragma unroll
                for (int j = 0; j < 20; ++j)
                    acc[i][j] = fmaf(a[i], w[j], acc[i][j]);
        }
    }

    // epilogue: relu(+men_part) then dot with types, reduce over e
    float sp[4] = {0.f, 0.f, 0.f, 0.f};
    #pragma unroll
    for (int i = 0; i < 4; ++i) {
        const float* mp = men_part + (size_t)(b0 + ty * 4 + i) * NEP;
        #pragma unroll
        for (int et = 0; et < 5; ++et) {
            float4 m4 = *(const float4*)(mp + et * 64 + tx * 4);
            float mm[4] = {m4.x, m4.y, m4.z, m4.w};
            #pragma unroll
            for (int j = 0; j < 4; ++j) {
                float h = fmaxf(acc[i][et * 4 + j] + mm[j], 0.0f);
                sp[i] += h * ts[et * 64 + tx * 4 + j];
            }
        }
    }
    // reduce across tx (16 consecutive lanes)
    #pragma unroll
    for (int i = 0; i < 4; ++i) {
        float v = sp[i];
        #pragma unroll
        for (int off = 1; off < 16; off <<= 1) v += __shfl_xor(v, off);
        if (tx == 0) scores[(size_t)t * NB + b0 + ty * 4 + i] = v;
    }
}

// ---------------------------------------------------------------------------
// Kernel 2: WARP loss. One block per batch row i.
// loss_i = sum_{j pos} rw[(bigger_j-1) mod n] * sum_{k neg} max(1+s_k-s_j, 0)
// ---------------------------------------------------------------------------
__global__ void loss_kernel(const float* __restrict__ scores,
                            const int* __restrict__ target,
                            float* __restrict__ out) {
    const int i = blockIdx.x;
    const int j = threadIdx.x;   // 0..127
    __shared__ float s[NT];
    __shared__ float rw[NT];
    __shared__ int   tg[NT];
    if (j < NT) {
        s[j]  = scores[(size_t)j * NB + i];
        tg[j] = target[(size_t)i * NT + j];
        double h = 0.0;
        for (int q = 1; q <= j; ++q) h += 1.0 / (double)q;
        rw[j] = (float)(1.0 + (double)j + h);   // rw[j] = 1 + j + H_j
    }
    __syncthreads();

    float contrib = 0.0f;
    if (j < NT && tg[j] == 1) {
        const float sj = s[j];
        int bigger = 0;
        float msum = 0.0f;
        for (int k = 0; k < NT; ++k) {
            if (tg[k] == 0) {
                float v = 1.0f + s[k] - sj;
                if (v > 0.0f) { bigger++; msum += v; }
            }
        }
        int r = (bigger + NT - 1) % NT;   // (bigger-1) mod n, Python semantics
        contrib = rw[r] * msum;
    }
    // block reduce: 2 waves
    #pragma unroll
    for (int off = 1; off < 64; off <<= 1) contrib += __shfl_xor(contrib, off);
    __shared__ float wsum[2];
    if ((threadIdx.x & 63) == 0) wsum[threadIdx.x >> 6] = contrib;
    __syncthreads();
    if (threadIdx.x == 0) atomicAdd(out, (wsum[0] + wsum[1]) * (1.0f / (float)NB));
}

// ---------------------------------------------------------------------------
extern "C" void kernel_launch(void* const* d_in, const int* in_sizes, int n_in,
                              void* d_out, int out_size, void* d_ws, size_t ws_size,
                              hipStream_t stream) {
    const float* ctx   = (const float*)d_in[0];   // (89, 1024, 1024)
    const float* men   = (const float*)d_in[1];   // (1024, 300)
    const float* types = (const float*)d_in[2];   // (89, 300)
    const float* W     = (const float*)d_in[3];   // (300, 1324)
    const float* bias  = (const float*)d_in[4];   // (300,)
    const int*   tgt   = (const int*)d_in[5];     // (1024, 89)
    float* out = (float*)d_out;

    float* men_part = (float*)d_ws;               // 1024*320 floats
    float* scores   = men_part + NB * NEP;        // 89*1024 floats

    hipMemsetAsync(d_out, 0, sizeof(float), stream);
    hipLaunchKernelGGL(menpart_kernel, dim3(NB), dim3(NEP), 0, stream,
                       men, W, bias, men_part);
    hipLaunchKernelGGL(scores_kernel, dim3(NB / BM, NT), dim3(256), 0, stream,
                       ctx, W, types, men_part, scores);
    hipLaunchKernelGGL(loss_kernel, dim3(NB), dim3(128), 0, stream,
                       scores, tgt, out);
}

// Round 3
// 766.822 us; speedup vs baseline: 1.7592x; 1.7592x over previous
//
#include <hip/hip_runtime.h>
#include <hip/hip_bf16.h>

// Problem constants
#define NT 89       // n_labels
#define NB 1024     // batch
#define NE 300      // word_emb
#define K1 1024     // ctx part of in_dim
#define NDIM 1324   // full in_dim

// GEMM tiling
#define BM 128      // b rows per block
#define BN 160      // e cols per block (2 blocks cover 320 padded)
#define BK 32       // k per step
#define SA 40       // LDS row stride in bf16 elems (80 B: 16B-aligned, low-conflict)

typedef short s8 __attribute__((ext_vector_type(8)));
typedef float f4 __attribute__((ext_vector_type(4)));

static __device__ inline unsigned bf16r(float x) {
    unsigned u = __float_as_uint(x);
    u += 0x7FFFu + ((u >> 16) & 1u);   // round-to-nearest-even
    return u >> 16;
}
static __device__ inline unsigned pack2(float x, float y) {
    return bf16r(x) | (bf16r(y) << 16);
}

// ---------------------------------------------------------------------------
// scores[t][b] = sum_e relu( [ctx[t,b,:], men[b,:]]·W[e,:] + bias[e] ) * types[t,e]
// Block: 128 b x 160 e for one t. 4 waves in 2(m) x 2(n).
// ---------------------------------------------------------------------------
__launch_bounds__(256, 2)
__global__ void scores_mfma_kernel(const float* __restrict__ ctx,
                                   const float* __restrict__ men,
                                   const float* __restrict__ W,
                                   const float* __restrict__ types,
                                   const float* __restrict__ bias,
                                   float* __restrict__ scores) {
    const int t  = blockIdx.z;
    const int b0 = blockIdx.x * BM;
    const int e0 = blockIdx.y * BN;
    const int tid = threadIdx.x;

    __shared__ unsigned short As[BM * SA];   // [row b][k] bf16
    __shared__ unsigned short Bs[BN * SA];   // [row e][k] bf16

    const int lane = tid & 63;
    const int wave = tid >> 6;
    const int wm = wave >> 1;           // 0/1 -> m half
    const int wn = wave & 1;            // 0/1 -> n half
    const int col = lane & 15;
    const int quad = lane >> 4;

    f4 acc[4][5];
    #pragma unroll
    for (int i = 0; i < 4; ++i)
        #pragma unroll
        for (int j = 0; j < 5; ++j) acc[i][j] = (f4)0.0f;

    const float* ctx_base = ctx + ((size_t)t * NB + b0) * K1;

    // ---------------- Phase 1: ctx part, K = 1024 ----------------
    for (int kt = 0; kt < K1 / BK; ++kt) {
        const int k0 = kt * BK;
        __syncthreads();
        // A: 128 rows x 32 k  (1024 float4-chunks / 256 thr = 4 passes)
        #pragma unroll
        for (int p = 0; p < 4; ++p) {
            int id = p * 256 + tid;
            int row = id >> 3, kv = id & 7;
            float4 v = *(const float4*)(ctx_base + (size_t)row * K1 + k0 + kv * 4);
            unsigned* dst = (unsigned*)&As[row * SA + kv * 4];
            dst[0] = pack2(v.x, v.y);
            dst[1] = pack2(v.z, v.w);
        }
        // B: 160 rows x 32 k (1280 chunks = 5 passes), zero rows e>=300
        #pragma unroll
        for (int p = 0; p < 5; ++p) {
            int id = p * 256 + tid;
            int row = id >> 3, kv = id & 7;
            int e = e0 + row;
            float4 v = make_float4(0.f, 0.f, 0.f, 0.f);
            if (e < NE) v = *(const float4*)(W + (size_t)e * NDIM + k0 + kv * 4);
            unsigned* dst = (unsigned*)&Bs[row * SA + kv * 4];
            dst[0] = pack2(v.x, v.y);
            dst[1] = pack2(v.z, v.w);
        }
        __syncthreads();

        s8 af[4], bf[5];
        #pragma unroll
        for (int i = 0; i < 4; ++i)
            af[i] = *(const s8*)&As[(wm * 64 + i * 16 + col) * SA + quad * 8];
        #pragma unroll
        for (int j = 0; j < 5; ++j)
            bf[j] = *(const s8*)&Bs[(wn * 80 + j * 16 + col) * SA + quad * 8];
        #pragma unroll
        for (int i = 0; i < 4; ++i)
            #pragma unroll
            for (int j = 0; j < 5; ++j)
                acc[i][j] = __builtin_amdgcn_mfma_f32_16x16x32_bf16(af[i], bf[j], acc[i][j], 0, 0, 0);
    }

    // ---------------- Phase 2: men part, K = 300 (10 steps of 32) ----------------
    for (int kt = 0; kt < 10; ++kt) {
        const int kd0 = kt * BK;
        __syncthreads();
        #pragma unroll
        for (int p = 0; p < 4; ++p) {
            int id = p * 256 + tid;
            int row = id >> 3, kv = id & 7;
            int kd = kd0 + kv * 4;
            float4 v = make_float4(0.f, 0.f, 0.f, 0.f);
            if (kd < NE) v = *(const float4*)(men + (size_t)(b0 + row) * NE + kd);
            unsigned* dst = (unsigned*)&As[row * SA + kv * 4];
            dst[0] = pack2(v.x, v.y);
            dst[1] = pack2(v.z, v.w);
        }
        #pragma unroll
        for (int p = 0; p < 5; ++p) {
            int id = p * 256 + tid;
            int row = id >> 3, kv = id & 7;
            int e = e0 + row;
            int kd = kd0 + kv * 4;
            float4 v = make_float4(0.f, 0.f, 0.f, 0.f);
            if (e < NE && kd < NE) v = *(const float4*)(W + (size_t)e * NDIM + K1 + kd);
            unsigned* dst = (unsigned*)&Bs[row * SA + kv * 4];
            dst[0] = pack2(v.x, v.y);
            dst[1] = pack2(v.z, v.w);
        }
        __syncthreads();

        s8 af[4], bf[5];
        #pragma unroll
        for (int i = 0; i < 4; ++i)
            af[i] = *(const s8*)&As[(wm * 64 + i * 16 + col) * SA + quad * 8];
        #pragma unroll
        for (int j = 0; j < 5; ++j)
            bf[j] = *(const s8*)&Bs[(wn * 80 + j * 16 + col) * SA + quad * 8];
        #pragma unroll
        for (int i = 0; i < 4; ++i)
            #pragma unroll
            for (int j = 0; j < 5; ++j)
                acc[i][j] = __builtin_amdgcn_mfma_f32_16x16x32_bf16(af[i], bf[j], acc[i][j], 0, 0, 0);
    }

    // ---------------- Epilogue: +bias, relu, *types, reduce over e ----------------
    float rowsum[4][4];
    #pragma unroll
    for (int i = 0; i < 4; ++i)
        #pragma unroll
        for (int r = 0; r < 4; ++r) rowsum[i][r] = 0.0f;

    #pragma unroll
    for (int j = 0; j < 5; ++j) {
        int e = e0 + wn * 80 + j * 16 + col;
        float tv = 0.0f, bv = 0.0f;
        if (e < NE) {
            tv = types[(size_t)t * NE + e];
            bv = bias[e];
        }
        #pragma unroll
        for (int i = 0; i < 4; ++i) {
            #pragma unroll
            for (int r = 0; r < 4; ++r) {
                float h = fmaxf(acc[i][j][r] + bv, 0.0f);
                rowsum[i][r] = fmaf(h, tv, rowsum[i][r]);
            }
        }
    }
    // butterfly reduce across the 16 e-lanes of each quad
    #pragma unroll
    for (int i = 0; i < 4; ++i)
        #pragma unroll
        for (int r = 0; r < 4; ++r) {
            float v = rowsum[i][r];
            #pragma unroll
            for (int off = 1; off < 16; off <<= 1) v += __shfl_xor(v, off);
            if (col == 0) {
                int row = b0 + wm * 64 + i * 16 + quad * 4 + r;
                atomicAdd(&scores[(size_t)t * NB + row], v);
            }
        }
}

// ---------------------------------------------------------------------------
// WARP loss. One block per batch row i.
// ---------------------------------------------------------------------------
__global__ void loss_kernel(const float* __restrict__ scores,
                            const int* __restrict__ target,
                            float* __restrict__ out) {
    const int i = blockIdx.x;
    const int j = threadIdx.x;   // 0..127
    __shared__ float s[NT];
    __shared__ float rw[NT];
    __shared__ int   tg[NT];
    if (j < NT) {
        s[j]  = scores[(size_t)j * NB + i];
        tg[j] = target[(size_t)i * NT + j];
        float h = 0.0f;
        for (int q = 1; q <= j; ++q) h += 1.0f / (float)q;
        rw[j] = 1.0f + (float)j + h;   // rw[j] = 1 + j + H_j
    }
    __syncthreads();

    float contrib = 0.0f;
    if (j < NT && tg[j] == 1) {
        const float sj = s[j];
        int bigger = 0;
        float msum = 0.0f;
        for (int k = 0; k < NT; ++k) {
            if (tg[k] == 0) {
                float v = 1.0f + s[k] - sj;
                if (v > 0.0f) { bigger++; msum += v; }
            }
        }
        int r = (bigger + NT - 1) % NT;   // (bigger-1) mod n, Python semantics
        contrib = rw[r] * msum;
    }
    #pragma unroll
    for (int off = 1; off < 64; off <<= 1) contrib += __shfl_xor(contrib, off);
    __shared__ float wsum[2];
    if ((threadIdx.x & 63) == 0) wsum[threadIdx.x >> 6] = contrib;
    __syncthreads();
    if (threadIdx.x == 0) atomicAdd(out, (wsum[0] + wsum[1]) * (1.0f / (float)NB));
}

// ---------------------------------------------------------------------------
extern "C" void kernel_launch(void* const* d_in, const int* in_sizes, int n_in,
                              void* d_out, int out_size, void* d_ws, size_t ws_size,
                              hipStream_t stream) {
    const float* ctx   = (const float*)d_in[0];   // (89, 1024, 1024)
    const float* men   = (const float*)d_in[1];   // (1024, 300)
    const float* types = (const float*)d_in[2];   // (89, 300)
    const float* W     = (const float*)d_in[3];   // (300, 1324)
    const float* bias  = (const float*)d_in[4];   // (300,)
    const int*   tgt   = (const int*)d_in[5];     // (1024, 89)
    float* out = (float*)d_out;

    float* scores = (float*)d_ws;                 // 89*1024 floats

    (void)hipMemsetAsync(d_out, 0, sizeof(float), stream);
    (void)hipMemsetAsync(scores, 0, (size_t)NT * NB * sizeof(float), stream);
    hipLaunchKernelGGL(scores_mfma_kernel, dim3(NB / BM, 2, NT), dim3(256), 0, stream,
                       ctx, men, W, types, bias, scores);
    hipLaunchKernelGGL(loss_kernel, dim3(NB), dim3(128), 0, stream,
                       scores, tgt, out);
}